// Round 5
// baseline (57.740 us; speedup 1.0000x reference)
//
#include <hip/hip_runtime.h>

constexpr int B = 8, N = 16384, C = 80, M = 100;
constexpr int NT = 64;           // n per block
constexpr int THREADS = 256;     // 4 waves; wave owns 16 n (1 row-frag)
constexpr int LDA = 104;         // fp16 stride for A tiles

typedef _Float16 half8 __attribute__((ext_vector_type(8)));
typedef _Float16 half4 __attribute__((ext_vector_type(4)));
typedef float f32x4 __attribute__((ext_vector_type(4)));

// ws layout (bytes):
//   ftab   : [B][3][7][64] uint4 = 172032 @ 0     (ct as packed fp16 B-fragments)
//   clsid  : B*M ints            =   3200 @ 172032
//   packed : B*M u64             =   6400 @ 175232 (8-aligned)
constexpr size_t WS_FTAB = 0;
constexpr size_t WS_CID  = 172032;
constexpr size_t WS_PACK = 175232;

__device__ __forceinline__ unsigned ford(float f) {
    unsigned u = __float_as_uint(f);
    return (u & 0x80000000u) ? ~u : (u | 0x80000000u);
}

__device__ __forceinline__ float rcpf(float x) { return __builtin_amdgcn_rcpf(x); }

// argmin-equivalent total (true total / 2); positive scaling preserves order.
__device__ __forceinline__ float pair_total(float cls,
    float4 p, float4 t, float a1, float a2)
{
    float ih = fminf(p.z, t.z) - fmaxf(p.x, t.x);
    float iw = fminf(p.w, t.w) - fmaxf(p.y, t.y);
    float inter = fmaxf(ih, 0.f) * fmaxf(iw, 0.f);
    float uni = a1 + a2 - inter;
    float iou = (uni > 0.f) ? inter * rcpf(uni) : 0.f;
    float eh = fmaxf(p.z, t.z) - fminf(p.x, t.x);
    float ew = fmaxf(p.w, t.w) - fminf(p.y, t.y);
    float enc = fmaxf(eh, 0.f) * fmaxf(ew, 0.f);
    float ue = (enc > 0.f) ? (1.f - uni * rcpf(enc)) : 0.f;   // (enc-uni)/enc
    float rg = fabsf(t.x - p.x) + fabsf(t.y - p.y) +
               fabsf(t.z - p.z) + fabsf(t.w - p.w);
    return fmaf(2.5f, rg, cls) + (1.f - iou + ue);
}

// Merged prep: waves [0, B*21) build ftab fragments; waves [B*21, B*21+B*M)
// build clsid + packed init.
__global__ void prep_kernel(const int* __restrict__ cls_true,
                            uint4* __restrict__ ftab,
                            int* __restrict__ clsid,
                            unsigned long long* __restrict__ packed)
{
    int wid = (blockIdx.x * blockDim.x + threadIdx.x) >> 6;
    int l = threadIdx.x & 63;
    if (wid < B * 21) {
        int b = wid / 21, rem = wid % 21, ch = rem / 7, mf = rem % 7;
        int m = mf * 16 + (l & 15);
        int c0 = ch * 32 + (l >> 4) * 8;
        unsigned w[4] = {0, 0, 0, 0};
        if (m < M) {
            const int* row = cls_true + ((size_t)b * M + m) * C;
            #pragma unroll
            for (int e = 0; e < 8; ++e) {
                int c = c0 + e;
                unsigned h = (c < C && row[c] == 1) ? 0x3C00u : 0u;  // fp16 1.0
                w[e >> 1] |= h << ((e & 1) * 16);
            }
        }
        ftab[(size_t)wid * 64 + l] = make_uint4(w[0], w[1], w[2], w[3]);
    } else if (wid < B * 21 + B * M) {
        int id = wid - B * 21;
        const int* row = cls_true + (size_t)id * C;
        bool v1 = (row[l] == 1);
        bool v2 = (l < 16) ? (row[64 + l] == 1) : false;
        unsigned long long m01 = __ballot(v1);
        unsigned long long m2  = __ballot(v2);
        if (l == 0) {
            int cid = 0;
            if (m01) cid = __ffsll(m01) - 1;
            else if (m2) cid = 64 + __ffsll(m2) - 1;
            clsid[id] = cid;
            packed[id] = 0xFFFFFFFFFFFFFFFFull;
        }
    }
}

__global__ __launch_bounds__(THREADS, 4)
void match_kernel(const float* __restrict__ cls_pred,
                  const float* __restrict__ loc_pred,
                  const uint4* __restrict__ ftab,
                  const float* __restrict__ loc_true,
                  unsigned long long* __restrict__ packed)
{
    __shared__ _Float16 s_hi[NT][LDA];            // 13312 B
    __shared__ _Float16 s_lo[NT][LDA];            // 13312 B
    __shared__ float s_lp[NT][4];                 //  1024 B
    __shared__ float s_lt[112][4];                //  1792 B
    __shared__ unsigned long long s_red[4][112];  //  3584 B  -> total 33024 B

    const int b  = blockIdx.y;
    const int n0 = blockIdx.x * NT;
    const int t  = threadIdx.x;
    const int l  = t & 63;
    const int wv = t >> 6;

    // ---- stage diff = pos-neg as fp16 hi + lo*2^-11 split ----
    const float4* cp4 = (const float4*)(cls_pred + ((size_t)b * N + n0) * C);
    for (int i = t; i < NT * C / 4; i += THREADS) {
        float4 v = cp4[i];
        int e = i * 4, nl = e / C, c = e % C;
        float pv[4] = { v.x, v.y, v.z, v.w };
        half4 hh, ll;
        #pragma unroll
        for (int j = 0; j < 4; ++j) {
            float p = pv[j], q = 1.0f - p;
            float pos = 0.25f * q * q * (-__logf(p + 1e-8f));
            float neg = 0.75f * p * p * (-__logf(q + 1e-8f));
            float d = pos - neg;
            _Float16 h = (_Float16)d;
            float rs = (d - (float)h) * 2048.0f;   // keep lo normal in fp16
            hh[j] = h;
            ll[j] = (_Float16)rs;
        }
        *(half4*)&s_hi[nl][c] = hh;
        *(half4*)&s_lo[nl][c] = ll;
    }
    // zero-pad c in [80,96)
    {
        int i = t;
        if (i < NT * 4) {
            int nl = i >> 2, c = C + (i & 3) * 4;
            half4 z = {0, 0, 0, 0};
            *(half4*)&s_hi[nl][c] = z;
            *(half4*)&s_lo[nl][c] = z;
        }
    }
    // boxes
    if (t < NT) {
        *(float4*)&s_lp[t][0] = ((const float4*)loc_pred)[(size_t)b * N + n0 + t];
    } else if (t < NT + 112) {
        int m = t - NT;
        float4 tb = (m < M) ? ((const float4*)loc_true)[(size_t)b * M + m]
                            : make_float4(0.f, 0.f, 0.f, 0.f);
        *(float4*)&s_lt[m][0] = tb;
    }
    __syncthreads();

    // ---- MFMA: D[n][m] = diff(n,c) . ct(c,m), fp16 2-split, one fp32 acc ----
    const int nw = wv * 16;
    f32x4 acc[7];
    #pragma unroll
    for (int mf = 0; mf < 7; ++mf) acc[mf] = f32x4{0.f, 0.f, 0.f, 0.f};

    const uint4* ft = ftab + (size_t)b * 21 * 64;
    const int arow = nw + (l & 15);
    const int acol = (l >> 4) * 8;

    #pragma unroll
    for (int kc = 0; kc < 3; ++kc) {
        half8 ah = *(const half8*)&s_hi[arow][kc * 32 + acol];
        half8 al = *(const half8*)&s_lo[arow][kc * 32 + acol];
        #pragma unroll
        for (int mf = 0; mf < 7; ++mf) {
            union { uint4 u; half8 h; } b1, b2;
            b1.u = ft[((size_t)kc * 7 + mf) * 64 + l];
            b2.u = make_uint4(b1.u.x & 0x10001000u, b1.u.y & 0x10001000u,
                              b1.u.z & 0x10001000u, b1.u.w & 0x10001000u); // ct*2^-11
            acc[mf] = __builtin_amdgcn_mfma_f32_16x16x32_f16(ah, b1.h, acc[mf], 0, 0, 0);
            acc[mf] = __builtin_amdgcn_mfma_f32_16x16x32_f16(al, b2.h, acc[mf], 0, 0, 0);
        }
    }

    // ---- epilogue: per-lane 4 n-boxes, per-mf m-box ----
    float4 bx[4];
    float a1[4];
    #pragma unroll
    for (int r = 0; r < 4; ++r) {
        int row = nw + (l >> 4) * 4 + r;
        float4 v = *(const float4*)&s_lp[row][0];
        bx[r] = v;
        a1[r] = fmaxf(v.z - v.x, 0.f) * fmaxf(v.w - v.y, 0.f);
    }

    #pragma unroll
    for (int mf = 0; mf < 7; ++mf) {
        float4 tb = *(const float4*)&s_lt[mf * 16 + (l & 15)][0];
        float a2 = fmaxf(tb.z - tb.x, 0.f) * fmaxf(tb.w - tb.y, 0.f);
        unsigned long long cand = 0xFFFFFFFFFFFFFFFFull;
        #pragma unroll
        for (int r = 0; r < 4; ++r) {
            float tot = pair_total(acc[mf][r], bx[r], tb, a1[r], a2);
            int n = n0 + nw + (l >> 4) * 4 + r;
            unsigned long long key =
                ((unsigned long long)ford(tot) << 32) | (unsigned)n;
            cand = (key < cand) ? key : cand;
        }
        #pragma unroll
        for (int off = 16; off <= 32; off <<= 1) {
            unsigned long long o = __shfl_xor(cand, off, 64);
            if (o < cand) cand = o;
        }
        if (l < 16) s_red[wv][mf * 16 + l] = cand;
    }
    __syncthreads();

    // ---- block reduce + one atomic per m ----
    if (t < 112) {
        unsigned long long v0 = s_red[0][t], v1 = s_red[1][t];
        unsigned long long v2 = s_red[2][t], v3 = s_red[3][t];
        unsigned long long a = v0 < v1 ? v0 : v1;
        unsigned long long c2 = v2 < v3 ? v2 : v3;
        a = a < c2 ? a : c2;
        if (t < M) atomicMin(&packed[(size_t)b * M + t], a);
    }
}

__global__ void out_kernel(const unsigned long long* __restrict__ packed,
                           const int* __restrict__ clsid,
                           int* __restrict__ out)
{
    int idx = blockIdx.x * blockDim.x + threadIdx.x;
    if (idx >= B * M) return;
    int b = idx / M;
    out[idx * 3 + 0] = b;
    out[idx * 3 + 1] = (int)(unsigned)(packed[idx] & 0xFFFFFFFFull);
    out[idx * 3 + 2] = clsid[idx];
}

extern "C" void kernel_launch(void* const* d_in, const int* in_sizes, int n_in,
                              void* d_out, int out_size, void* d_ws, size_t ws_size,
                              hipStream_t stream)
{
    const float* cls_pred = (const float*)d_in[0];
    const float* loc_pred = (const float*)d_in[1];
    const int*   cls_true = (const int*)d_in[2];
    const float* loc_true = (const float*)d_in[3];
    // d_in[4] = reg_mask (unused by the reference output)

    char* ws = (char*)d_ws;
    uint4* ftab = (uint4*)(ws + WS_FTAB);
    int*   clsid = (int*)(ws + WS_CID);
    unsigned long long* packed = (unsigned long long*)(ws + WS_PACK);

    int* out = (int*)d_out;

    int prep_waves = B * 21 + B * M;   // 968
    prep_kernel<<<(prep_waves * 64 + 255) / 256, 256, 0, stream>>>(
        cls_true, ftab, clsid, packed);

    dim3 grid(N / NT, B);
    match_kernel<<<grid, THREADS, 0, stream>>>(
        cls_pred, loc_pred, ftab, loc_true, packed);

    out_kernel<<<(B * M + 255) / 256, 256, 0, stream>>>(packed, clsid, out);
}